// Round 2
// baseline (644.336 us; speedup 1.0000x reference)
//
#include <hip/hip_runtime.h>
#include <hip/hip_bf16.h>
#include <math.h>

// Problem dims (fixed by the reference)
#define B_   4
#define L_   4096
#define D_   2048
#define N_   16
#define R_   64          // DT_RANK
#define E_   96          // R_ + 2*N_
#define NCH  32          // chunks over L
#define CH   (L_ / NCH)  // 128 steps per chunk

#define LOG2E 1.44269504088896340736f

#if __has_builtin(__builtin_amdgcn_exp2f)
#define EXP2F(x) __builtin_amdgcn_exp2f(x)
#else
#define EXP2F(x) exp2f(x)
#endif

// ---------------------------------------------------------------------------
// K0: A2[d][n] = -exp(A_log[d][n]) * log2(e)   (so dA = exp2(dt * A2))
// ---------------------------------------------------------------------------
__global__ void k_prep(const float* __restrict__ A_log, float* __restrict__ A2) {
    int i = blockIdx.x * 256 + threadIdx.x;
    if (i < D_ * N_) A2[i] = -__expf(A_log[i]) * LOG2E;
}

// ---------------------------------------------------------------------------
// K1: xp = x @ W_x     (M=B*L=16384, K=2048, Ncols=96), fp32 VALU GEMM
// block: 256 threads, tile 64 rows x 96 cols, BK=16
// ---------------------------------------------------------------------------
__global__ __launch_bounds__(256) void k_proj(const float* __restrict__ x,
                                              const float* __restrict__ Wx,
                                              float* __restrict__ xp) {
    __shared__ float xs[16][68];   // [k][row], padded, 16B-aligned rows
    __shared__ float wsm[16][96];  // [k][col]
    const int t  = threadIdx.x;
    const int tx = t & 15;         // col group 0..15
    const int ty = t >> 4;         // row group 0..15
    const int row0 = blockIdx.x * 64;

    float acc[4][6];
#pragma unroll
    for (int i = 0; i < 4; i++)
#pragma unroll
        for (int j = 0; j < 6; j++) acc[i][j] = 0.f;

    const int lrow = t >> 2;        // 0..63
    const int lk   = (t & 3) * 4;   // 0,4,8,12

    for (int k0 = 0; k0 < 2048; k0 += 16) {
        __syncthreads();
        // x tile 64x16 -> transposed LDS
        float4 xv = *(const float4*)(x + (size_t)(row0 + lrow) * 2048 + k0 + lk);
        xs[lk + 0][lrow] = xv.x;
        xs[lk + 1][lrow] = xv.y;
        xs[lk + 2][lrow] = xv.z;
        xs[lk + 3][lrow] = xv.w;
        // W tile 16x96
#pragma unroll
        for (int j = 0; j < 6; j++) {
            int idx = t + j * 256;      // 0..1535
            int kk = idx / 96;
            int cc = idx - kk * 96;
            wsm[kk][cc] = Wx[(size_t)(k0 + kk) * 96 + cc];
        }
        __syncthreads();
#pragma unroll
        for (int k = 0; k < 16; k++) {
            float a[4], w[6];
#pragma unroll
            for (int i = 0; i < 4; i++) a[i] = xs[k][ty * 4 + i];
#pragma unroll
            for (int j = 0; j < 6; j++) w[j] = wsm[k][tx + j * 16];
#pragma unroll
            for (int i = 0; i < 4; i++)
#pragma unroll
                for (int j = 0; j < 6; j++)
                    acc[i][j] = fmaf(a[i], w[j], acc[i][j]);
        }
    }
#pragma unroll
    for (int i = 0; i < 4; i++)
#pragma unroll
        for (int j = 0; j < 6; j++)
            xp[(size_t)(row0 + ty * 4 + i) * 96 + tx + j * 16] = acc[i][j];
}

// ---------------------------------------------------------------------------
// K2: dt = softplus(xp[:, :64] @ W_dt + b_dt) -> written into d_out (staging)
// block: 256 threads, tile 32 rows x 128 cols, K=64 (single tile)
// ---------------------------------------------------------------------------
__global__ __launch_bounds__(256) void k_dt(const float* __restrict__ xp,
                                            const float* __restrict__ Wdt,
                                            const float* __restrict__ bdt,
                                            float* __restrict__ dt) {
    __shared__ float as[64][34];    // [k][row]
    __shared__ float ws2[64][128];  // [k][col]
    const int t  = threadIdx.x;
    const int tx = t & 15;          // 0..15
    const int ty = t >> 4;          // 0..15
    const int m0 = blockIdx.x * 32;
    const int n0 = blockIdx.y * 128;

    {   // load A tile: 32 rows x 64 cols (dt_low part of xp)
        int row = t >> 3;           // 0..31
        int kq  = (t & 7) * 8;      // 0..56
        const float4* p = (const float4*)(xp + (size_t)(m0 + row) * 96 + kq);
        float4 v0 = p[0], v1 = p[1];
        as[kq + 0][row] = v0.x; as[kq + 1][row] = v0.y;
        as[kq + 2][row] = v0.z; as[kq + 3][row] = v0.w;
        as[kq + 4][row] = v1.x; as[kq + 5][row] = v1.y;
        as[kq + 6][row] = v1.z; as[kq + 7][row] = v1.w;
    }
    {   // load W tile 64x128
#pragma unroll
        for (int j = 0; j < 8; j++) {
            int ci = t + j * 256;        // 0..2047 chunk of 4 floats
            int kk = ci >> 5;            // 0..63
            int cc = (ci & 31) * 4;      // 0..124
            float4 v = *(const float4*)(Wdt + (size_t)kk * 2048 + n0 + cc);
            *(float4*)&ws2[kk][cc] = v;
        }
    }
    __syncthreads();

    const int r0 = ty * 2;
    float acc[2][8];
#pragma unroll
    for (int i = 0; i < 2; i++)
#pragma unroll
        for (int j = 0; j < 8; j++) acc[i][j] = 0.f;

#pragma unroll 8
    for (int k = 0; k < 64; k++) {
        float a0 = as[k][r0], a1 = as[k][r0 + 1];
#pragma unroll
        for (int j = 0; j < 8; j++) {
            float w = ws2[k][tx + j * 16];
            acc[0][j] = fmaf(a0, w, acc[0][j]);
            acc[1][j] = fmaf(a1, w, acc[1][j]);
        }
    }
#pragma unroll
    for (int i = 0; i < 2; i++)
#pragma unroll
        for (int j = 0; j < 8; j++) {
            int c = n0 + tx + j * 16;
            float z = acc[i][j] + bdt[c];
            float v = (z > 20.f) ? z : log1pf(__expf(z));
            dt[(size_t)(m0 + r0 + i) * 2048 + c] = v;
        }
}

// ---------------------------------------------------------------------------
// K3: scan pass 1 — per chunk: local h (h0=0) and sum(dt) over the chunk
// grid: b(4) x chunk(32) x dtile(8); block 256 threads, 1 channel/thread
// ---------------------------------------------------------------------------
__global__ __launch_bounds__(256) void k_scan1(const float* __restrict__ dt,
                                               const float* __restrict__ x,
                                               const float* __restrict__ xp,
                                               const float* __restrict__ A2,
                                               float* __restrict__ hend,
                                               float* __restrict__ sdtb) {
    const int t = threadIdx.x;
    int bb = blockIdx.x;
    const int dtile = bb & 7;  bb >>= 3;
    const int c     = bb & 31; bb >>= 5;
    const int b     = bb;
    const int d = dtile * 256 + t;

    float a2[16];
    {
        const float4* p = (const float4*)(A2 + (size_t)d * 16);
        float4 v0 = p[0], v1 = p[1], v2 = p[2], v3 = p[3];
        a2[0]=v0.x; a2[1]=v0.y; a2[2]=v0.z; a2[3]=v0.w;
        a2[4]=v1.x; a2[5]=v1.y; a2[6]=v1.z; a2[7]=v1.w;
        a2[8]=v2.x; a2[9]=v2.y; a2[10]=v2.z; a2[11]=v2.w;
        a2[12]=v3.x; a2[13]=v3.y; a2[14]=v3.z; a2[15]=v3.w;
    }
    float h[16];
#pragma unroll
    for (int n = 0; n < 16; n++) h[n] = 0.f;
    float sdt = 0.f;

    const int tstart = c * CH;
    size_t base = ((size_t)b * L_ + tstart) * D_ + d;
    const float* xprow = xp + ((size_t)b * L_ + tstart) * E_;

    for (int s = 0; s < CH; s++) {
        float dtv = dt[base];
        float xv  = x[base];
        base += D_;
        const float4* p4 = (const float4*)(xprow + R_);
        float4 b0 = p4[0], b1 = p4[1], b2 = p4[2], b3 = p4[3];
        xprow += E_;
        float bv[16] = {b0.x,b0.y,b0.z,b0.w, b1.x,b1.y,b1.z,b1.w,
                        b2.x,b2.y,b2.z,b2.w, b3.x,b3.y,b3.z,b3.w};
        float u = dtv * xv;
        sdt += dtv;
#pragma unroll
        for (int n = 0; n < 16; n++) {
            float dA = EXP2F(dtv * a2[n]);
            h[n] = fmaf(dA, h[n], u * bv[n]);
        }
    }

    size_t hb = ((((size_t)b * NCH + c) * D_) + d) * N_;
#pragma unroll
    for (int q = 0; q < 4; q++) {
        float4 v = make_float4(h[q*4+0], h[q*4+1], h[q*4+2], h[q*4+3]);
        *(float4*)(hend + hb + q * 4) = v;
    }
    sdtb[((size_t)b * NCH + c) * D_ + d] = sdt;
}

// ---------------------------------------------------------------------------
// K4: chain chunk states: hinit[c] = P[c-1]*hinit[c-1] + hend[c-1]
//     (in-place: hend slot c is overwritten with hinit[c])
// ---------------------------------------------------------------------------
__global__ void k_comb(const float* __restrict__ A2,
                       const float* __restrict__ sdtb,
                       float* __restrict__ hend) {
    int g = blockIdx.x * 256 + threadIdx.x;   // 0 .. B*D*N-1
    int n = g & 15;
    int d = (g >> 4) & (D_ - 1);
    int b = g >> 15;
    float a2 = A2[(size_t)d * 16 + n];
    float carry = 0.f;
    for (int c = 0; c < NCH; c++) {
        size_t hi = ((((size_t)b * NCH + c) * D_) + d) * N_ + n;
        float e = hend[hi];
        float p = EXP2F(sdtb[((size_t)b * NCH + c) * D_ + d] * a2);
        hend[hi] = carry;                 // now holds hinit for chunk c
        carry = fmaf(p, carry, e);
    }
}

// ---------------------------------------------------------------------------
// K5: scan pass 2 — h starts at hinit, emit y = scan + x*D_skip
//     dty holds dt on input (d_out), overwritten element-wise with y
// ---------------------------------------------------------------------------
__global__ __launch_bounds__(256) void k_scan2(float* __restrict__ dty,
                                               const float* __restrict__ x,
                                               const float* __restrict__ xp,
                                               const float* __restrict__ A2,
                                               const float* __restrict__ hinit,
                                               const float* __restrict__ Dskip) {
    const int t = threadIdx.x;
    int bb = blockIdx.x;
    const int dtile = bb & 7;  bb >>= 3;
    const int c     = bb & 31; bb >>= 5;
    const int b     = bb;
    const int d = dtile * 256 + t;

    float a2[16];
    {
        const float4* p = (const float4*)(A2 + (size_t)d * 16);
        float4 v0 = p[0], v1 = p[1], v2 = p[2], v3 = p[3];
        a2[0]=v0.x; a2[1]=v0.y; a2[2]=v0.z; a2[3]=v0.w;
        a2[4]=v1.x; a2[5]=v1.y; a2[6]=v1.z; a2[7]=v1.w;
        a2[8]=v2.x; a2[9]=v2.y; a2[10]=v2.z; a2[11]=v2.w;
        a2[12]=v3.x; a2[13]=v3.y; a2[14]=v3.z; a2[15]=v3.w;
    }
    float h[16];
    {
        size_t hb = ((((size_t)b * NCH + c) * D_) + d) * N_;
        const float4* p = (const float4*)(hinit + hb);
        float4 v0 = p[0], v1 = p[1], v2 = p[2], v3 = p[3];
        h[0]=v0.x; h[1]=v0.y; h[2]=v0.z; h[3]=v0.w;
        h[4]=v1.x; h[5]=v1.y; h[6]=v1.z; h[7]=v1.w;
        h[8]=v2.x; h[9]=v2.y; h[10]=v2.z; h[11]=v2.w;
        h[12]=v3.x; h[13]=v3.y; h[14]=v3.z; h[15]=v3.w;
    }
    const float dsk = Dskip[d];

    const int tstart = c * CH;
    size_t base = ((size_t)b * L_ + tstart) * D_ + d;
    const float* xprow = xp + ((size_t)b * L_ + tstart) * E_;

    for (int s = 0; s < CH; s++) {
        float dtv = dty[base];
        float xv  = x[base];
        const float4* p4 = (const float4*)(xprow + R_);
        float4 b0 = p4[0], b1 = p4[1], b2 = p4[2], b3 = p4[3];
        float4 c0 = p4[4], c1 = p4[5], c2 = p4[6], c3 = p4[7];
        xprow += E_;
        float bv[16] = {b0.x,b0.y,b0.z,b0.w, b1.x,b1.y,b1.z,b1.w,
                        b2.x,b2.y,b2.z,b2.w, b3.x,b3.y,b3.z,b3.w};
        float cv[16] = {c0.x,c0.y,c0.z,c0.w, c1.x,c1.y,c1.z,c1.w,
                        c2.x,c2.y,c2.z,c2.w, c3.x,c3.y,c3.z,c3.w};
        float u = dtv * xv;
        float y0 = 0.f, y1 = 0.f, y2 = 0.f, y3 = 0.f;
#pragma unroll
        for (int n = 0; n < 16; n += 4) {
            float dA0 = EXP2F(dtv * a2[n + 0]);
            float dA1 = EXP2F(dtv * a2[n + 1]);
            float dA2 = EXP2F(dtv * a2[n + 2]);
            float dA3 = EXP2F(dtv * a2[n + 3]);
            h[n + 0] = fmaf(dA0, h[n + 0], u * bv[n + 0]);
            h[n + 1] = fmaf(dA1, h[n + 1], u * bv[n + 1]);
            h[n + 2] = fmaf(dA2, h[n + 2], u * bv[n + 2]);
            h[n + 3] = fmaf(dA3, h[n + 3], u * bv[n + 3]);
            y0 = fmaf(h[n + 0], cv[n + 0], y0);
            y1 = fmaf(h[n + 1], cv[n + 1], y1);
            y2 = fmaf(h[n + 2], cv[n + 2], y2);
            y3 = fmaf(h[n + 3], cv[n + 3], y3);
        }
        float y = (y0 + y1) + (y2 + y3);
        dty[base] = fmaf(xv, dsk, y);   // overwrite dt with final y
        base += D_;
    }
}

// ---------------------------------------------------------------------------
extern "C" void kernel_launch(void* const* d_in, const int* in_sizes, int n_in,
                              void* d_out, int out_size, void* d_ws, size_t ws_size,
                              hipStream_t stream) {
    const float* x     = (const float*)d_in[0];
    const float* A_log = (const float*)d_in[1];
    const float* Dskip = (const float*)d_in[2];
    const float* Wx    = (const float*)d_in[3];
    const float* Wdt   = (const float*)d_in[4];
    const float* bdt   = (const float*)d_in[5];
    float* out = (float*)d_out;

    float* ws   = (float*)d_ws;
    float* A2   = ws;                       // 32768 floats
    float* xp   = A2 + 32768;               // 16384*96 = 1572864
    float* hend = xp + 1572864;             // 4*32*2048*16 = 4194304
    float* sdtb = hend + 4194304;           // 4*32*2048 = 262144
    // total ~24.2 MB of workspace

    hipLaunchKernelGGL(k_prep, dim3(128), dim3(256), 0, stream, A_log, A2);
    hipLaunchKernelGGL(k_proj, dim3(256), dim3(256), 0, stream, x, Wx, xp);
    hipLaunchKernelGGL(k_dt, dim3(512, 16), dim3(256), 0, stream, xp, Wdt, bdt, out);
    hipLaunchKernelGGL(k_scan1, dim3(B_ * NCH * 8), dim3(256), 0, stream,
                       out, x, xp, A2, hend, sdtb);
    hipLaunchKernelGGL(k_comb, dim3((B_ * D_ * N_) / 256), dim3(256), 0, stream,
                       A2, sdtb, hend);
    hipLaunchKernelGGL(k_scan2, dim3(B_ * NCH * 8), dim3(256), 0, stream,
                       out, x, xp, A2, hend, Dskip);
}

// Round 3
// 475.923 us; speedup vs baseline: 1.3539x; 1.3539x over previous
//
#include <hip/hip_runtime.h>
#include <hip/hip_bf16.h>
#include <math.h>

// Problem dims (fixed by the reference)
#define B_   4
#define L_   4096
#define D_   2048
#define N_   16
#define R_   64          // DT_RANK
#define E_   96          // R_ + 2*N_
#define NCH  32          // chunks over L
#define CH   (L_ / NCH)  // 128 steps per chunk

#define LOG2E 1.44269504088896340736f

#if __has_builtin(__builtin_amdgcn_exp2f)
#define EXP2F(x) __builtin_amdgcn_exp2f(x)
#else
#define EXP2F(x) exp2f(x)
#endif

typedef __attribute__((ext_vector_type(8))) short short8v;   // 8 bf16 (4 VGPR)
typedef __attribute__((ext_vector_type(4))) float float4v;   // MFMA C/D

// ---------------------------------------------------------------------------
// K0: A2[d][n] = -exp(A_log[d][n]) * log2(e)   (so dA = exp2(dt * A2))
// ---------------------------------------------------------------------------
__global__ void k_prep(const float* __restrict__ A_log, float* __restrict__ A2) {
    int i = blockIdx.x * 256 + threadIdx.x;
    if (i < D_ * N_) A2[i] = -__expf(A_log[i]) * LOG2E;
}

// ---------------------------------------------------------------------------
// K0b: pack W_x into MFMA B-fragment order, split hi/lo bf16.
// B frag (16x16x32): lane l, elem j -> B[k = s*32 + (l>>4)*8 + j][col = c*16 + (l&15)]
// index: ((c*64 + s)*64 + l)*8 + j   (c=coltile 0..5, s=kstep 0..63)
// ---------------------------------------------------------------------------
__global__ void k_packB(const float* __restrict__ Wx,
                        ushort* __restrict__ Bh, ushort* __restrict__ Bl) {
    int i = blockIdx.x * 256 + threadIdx.x;   // 0 .. 6*64*64*8-1
    int j = i & 7;
    int l = (i >> 3) & 63;
    int s = (i >> 9) & 63;
    int c = i >> 15;                           // 0..5
    int k   = s * 32 + ((l >> 4) << 3) + j;
    int col = c * 16 + (l & 15);
    float v = Wx[(size_t)k * 96 + col];
    unsigned int b  = __float_as_uint(v);
    unsigned int hb = b & 0xFFFF0000u;         // truncated bf16 (exact residual)
    float dl = v - __uint_as_float(hb);
    Bh[i] = (ushort)(hb >> 16);
    Bl[i] = (ushort)(__float_as_uint(dl) >> 16);
}

// ---------------------------------------------------------------------------
// K1: xp = x @ W_x  via split-bf16 MFMA (3 mfma per tile: hh + hl + lh)
// block: 256 thr = 4 waves = 2 row-groups x 2 K-halves; tile M=32, all 96 cols
// grid 512 -> 2 blocks/CU. x read exactly once (coalesced float4 pairs).
// ---------------------------------------------------------------------------
__global__ __launch_bounds__(256) void k_projm(const float* __restrict__ x,
                                               const ushort* __restrict__ Bh,
                                               const ushort* __restrict__ Bl,
                                               float* __restrict__ xp) {
    __shared__ float red[2][64][24];   // K-half-1 partials: [rowgrp][lane][6*4]
    const int t    = threadIdx.x;
    const int lane = t & 63;
    const int w    = t >> 6;     // 0..3
    const int rg   = w & 1;      // row group
    const int kh   = w >> 1;     // K half
    const int row0 = blockIdx.x * 32 + rg * 16;
    const int r    = lane & 15;
    const int ko   = (lane >> 4) << 3;   // 0,8,16,24 within the 32-K step

    float4v acc[6];
#pragma unroll
    for (int c = 0; c < 6; c++) acc[c] = (float4v)(0.f);

    const float* xrow = x + (size_t)(row0 + r) * 2048 + kh * 1024 + ko;

#pragma unroll 2
    for (int sl = 0; sl < 32; ++sl) {
        float4 xa = *(const float4*)(xrow);
        float4 xb = *(const float4*)(xrow + 4);
        xrow += 32;
        short8v ah, al;
        {
            float xs8[8] = {xa.x, xa.y, xa.z, xa.w, xb.x, xb.y, xb.z, xb.w};
#pragma unroll
            for (int j = 0; j < 8; j++) {
                unsigned int b  = __float_as_uint(xs8[j]);
                unsigned int hb = b & 0xFFFF0000u;
                ah[j] = (short)(hb >> 16);
                float dl = xs8[j] - __uint_as_float(hb);
                al[j] = (short)(__float_as_uint(dl) >> 16);
            }
        }
        const int s = kh * 32 + sl;
        const ushort* bhp = Bh + ((size_t)s * 64 + lane) * 8;
        const ushort* blp = Bl + ((size_t)s * 64 + lane) * 8;
#pragma unroll
        for (int c = 0; c < 6; c++) {
            short8v bh = *(const short8v*)(bhp + (size_t)c * 32768);
            short8v bl = *(const short8v*)(blp + (size_t)c * 32768);
            acc[c] = __builtin_amdgcn_mfma_f32_16x16x32_bf16(ah, bh, acc[c], 0, 0, 0);
            acc[c] = __builtin_amdgcn_mfma_f32_16x16x32_bf16(ah, bl, acc[c], 0, 0, 0);
            acc[c] = __builtin_amdgcn_mfma_f32_16x16x32_bf16(al, bh, acc[c], 0, 0, 0);
        }
    }

    // combine K halves: kh==1 waves dump partials to LDS, kh==0 waves add+store
    if (kh == 1) {
#pragma unroll
        for (int c = 0; c < 6; c++)
            *(float4*)&red[rg][lane][c * 4] = make_float4(acc[c][0], acc[c][1],
                                                          acc[c][2], acc[c][3]);
    }
    __syncthreads();
    if (kh == 0) {
#pragma unroll
        for (int c = 0; c < 6; c++) {
            float4 o = *(const float4*)&red[rg][lane][c * 4];
            float v0 = acc[c][0] + o.x;
            float v1 = acc[c][1] + o.y;
            float v2 = acc[c][2] + o.z;
            float v3 = acc[c][3] + o.w;
            // D layout: col = lane&15, row = (lane>>4)*4 + j
            int col = c * 16 + (lane & 15);
            size_t rowb = (size_t)(row0 + ((lane >> 4) << 2));
            xp[(rowb + 0) * 96 + col] = v0;
            xp[(rowb + 1) * 96 + col] = v1;
            xp[(rowb + 2) * 96 + col] = v2;
            xp[(rowb + 3) * 96 + col] = v3;
        }
    }
}

// ---------------------------------------------------------------------------
// K2: dt = softplus(xp[:, :64] @ W_dt + b_dt) -> written into d_out (staging)
// ---------------------------------------------------------------------------
__global__ __launch_bounds__(256) void k_dt(const float* __restrict__ xp,
                                            const float* __restrict__ Wdt,
                                            const float* __restrict__ bdt,
                                            float* __restrict__ dt) {
    __shared__ float as[64][34];    // [k][row]
    __shared__ float ws2[64][128];  // [k][col]
    const int t  = threadIdx.x;
    const int tx = t & 15;          // 0..15
    const int ty = t >> 4;          // 0..15
    const int m0 = blockIdx.x * 32;
    const int n0 = blockIdx.y * 128;

    {   // load A tile: 32 rows x 64 cols (dt_low part of xp)
        int row = t >> 3;           // 0..31
        int kq  = (t & 7) * 8;      // 0..56
        const float4* p = (const float4*)(xp + (size_t)(m0 + row) * 96 + kq);
        float4 v0 = p[0], v1 = p[1];
        as[kq + 0][row] = v0.x; as[kq + 1][row] = v0.y;
        as[kq + 2][row] = v0.z; as[kq + 3][row] = v0.w;
        as[kq + 4][row] = v1.x; as[kq + 5][row] = v1.y;
        as[kq + 6][row] = v1.z; as[kq + 7][row] = v1.w;
    }
    {   // load W tile 64x128
#pragma unroll
        for (int j = 0; j < 8; j++) {
            int ci = t + j * 256;
            int kk = ci >> 5;
            int cc = (ci & 31) * 4;
            float4 v = *(const float4*)(Wdt + (size_t)kk * 2048 + n0 + cc);
            *(float4*)&ws2[kk][cc] = v;
        }
    }
    __syncthreads();

    const int r0 = ty * 2;
    float acc[2][8];
#pragma unroll
    for (int i = 0; i < 2; i++)
#pragma unroll
        for (int j = 0; j < 8; j++) acc[i][j] = 0.f;

#pragma unroll 8
    for (int k = 0; k < 64; k++) {
        float a0 = as[k][r0], a1 = as[k][r0 + 1];
#pragma unroll
        for (int j = 0; j < 8; j++) {
            float w = ws2[k][tx + j * 16];
            acc[0][j] = fmaf(a0, w, acc[0][j]);
            acc[1][j] = fmaf(a1, w, acc[1][j]);
        }
    }
#pragma unroll
    for (int i = 0; i < 2; i++)
#pragma unroll
        for (int j = 0; j < 8; j++) {
            int c = n0 + tx + j * 16;
            float z = acc[i][j] + bdt[c];
            float v = (z > 20.f) ? z : log1pf(__expf(z));
            dt[(size_t)(m0 + r0 + i) * 2048 + c] = v;
        }
}

// ---------------------------------------------------------------------------
// K3: scan pass 1 — per chunk: local h (h0=0) and sum(dt) over the chunk
// ---------------------------------------------------------------------------
__global__ __launch_bounds__(256) void k_scan1(const float* __restrict__ dt,
                                               const float* __restrict__ x,
                                               const float* __restrict__ xp,
                                               const float* __restrict__ A2,
                                               float* __restrict__ hend,
                                               float* __restrict__ sdtb) {
    const int t = threadIdx.x;
    int bb = blockIdx.x;
    const int dtile = bb & 7;  bb >>= 3;
    const int c     = bb & 31; bb >>= 5;
    const int b     = bb;
    const int d = dtile * 256 + t;

    float a2[16];
    {
        const float4* p = (const float4*)(A2 + (size_t)d * 16);
        float4 v0 = p[0], v1 = p[1], v2 = p[2], v3 = p[3];
        a2[0]=v0.x; a2[1]=v0.y; a2[2]=v0.z; a2[3]=v0.w;
        a2[4]=v1.x; a2[5]=v1.y; a2[6]=v1.z; a2[7]=v1.w;
        a2[8]=v2.x; a2[9]=v2.y; a2[10]=v2.z; a2[11]=v2.w;
        a2[12]=v3.x; a2[13]=v3.y; a2[14]=v3.z; a2[15]=v3.w;
    }
    float h[16];
#pragma unroll
    for (int n = 0; n < 16; n++) h[n] = 0.f;
    float sdt = 0.f;

    const int tstart = c * CH;
    size_t base = ((size_t)b * L_ + tstart) * D_ + d;
    const float* xprow = xp + ((size_t)b * L_ + tstart) * E_;

    for (int s = 0; s < CH; s++) {
        float dtv = dt[base];
        float xv  = x[base];
        base += D_;
        const float4* p4 = (const float4*)(xprow + R_);
        float4 b0 = p4[0], b1 = p4[1], b2 = p4[2], b3 = p4[3];
        xprow += E_;
        float bv[16] = {b0.x,b0.y,b0.z,b0.w, b1.x,b1.y,b1.z,b1.w,
                        b2.x,b2.y,b2.z,b2.w, b3.x,b3.y,b3.z,b3.w};
        float u = dtv * xv;
        sdt += dtv;
#pragma unroll
        for (int n = 0; n < 16; n++) {
            float dA = EXP2F(dtv * a2[n]);
            h[n] = fmaf(dA, h[n], u * bv[n]);
        }
    }

    size_t hb = ((((size_t)b * NCH + c) * D_) + d) * N_;
#pragma unroll
    for (int q = 0; q < 4; q++) {
        float4 v = make_float4(h[q*4+0], h[q*4+1], h[q*4+2], h[q*4+3]);
        *(float4*)(hend + hb + q * 4) = v;
    }
    sdtb[((size_t)b * NCH + c) * D_ + d] = sdt;
}

// ---------------------------------------------------------------------------
// K4: chain chunk states: hinit[c] = P[c-1]*hinit[c-1] + hend[c-1]
// ---------------------------------------------------------------------------
__global__ void k_comb(const float* __restrict__ A2,
                       const float* __restrict__ sdtb,
                       float* __restrict__ hend) {
    int g = blockIdx.x * 256 + threadIdx.x;   // 0 .. B*D*N-1
    int n = g & 15;
    int d = (g >> 4) & (D_ - 1);
    int b = g >> 15;
    float a2 = A2[(size_t)d * 16 + n];
    float carry = 0.f;
    for (int c = 0; c < NCH; c++) {
        size_t hi = ((((size_t)b * NCH + c) * D_) + d) * N_ + n;
        float e = hend[hi];
        float p = EXP2F(sdtb[((size_t)b * NCH + c) * D_ + d] * a2);
        hend[hi] = carry;                 // now holds hinit for chunk c
        carry = fmaf(p, carry, e);
    }
}

// ---------------------------------------------------------------------------
// K5: scan pass 2 — h starts at hinit, emit y = scan + x*D_skip
// ---------------------------------------------------------------------------
__global__ __launch_bounds__(256) void k_scan2(float* __restrict__ dty,
                                               const float* __restrict__ x,
                                               const float* __restrict__ xp,
                                               const float* __restrict__ A2,
                                               const float* __restrict__ hinit,
                                               const float* __restrict__ Dskip) {
    const int t = threadIdx.x;
    int bb = blockIdx.x;
    const int dtile = bb & 7;  bb >>= 3;
    const int c     = bb & 31; bb >>= 5;
    const int b     = bb;
    const int d = dtile * 256 + t;

    float a2[16];
    {
        const float4* p = (const float4*)(A2 + (size_t)d * 16);
        float4 v0 = p[0], v1 = p[1], v2 = p[2], v3 = p[3];
        a2[0]=v0.x; a2[1]=v0.y; a2[2]=v0.z; a2[3]=v0.w;
        a2[4]=v1.x; a2[5]=v1.y; a2[6]=v1.z; a2[7]=v1.w;
        a2[8]=v2.x; a2[9]=v2.y; a2[10]=v2.z; a2[11]=v2.w;
        a2[12]=v3.x; a2[13]=v3.y; a2[14]=v3.z; a2[15]=v3.w;
    }
    float h[16];
    {
        size_t hb = ((((size_t)b * NCH + c) * D_) + d) * N_;
        const float4* p = (const float4*)(hinit + hb);
        float4 v0 = p[0], v1 = p[1], v2 = p[2], v3 = p[3];
        h[0]=v0.x; h[1]=v0.y; h[2]=v0.z; h[3]=v0.w;
        h[4]=v1.x; h[5]=v1.y; h[6]=v1.z; h[7]=v1.w;
        h[8]=v2.x; h[9]=v2.y; h[10]=v2.z; h[11]=v2.w;
        h[12]=v3.x; h[13]=v3.y; h[14]=v3.z; h[15]=v3.w;
    }
    const float dsk = Dskip[d];

    const int tstart = c * CH;
    size_t base = ((size_t)b * L_ + tstart) * D_ + d;
    const float* xprow = xp + ((size_t)b * L_ + tstart) * E_;

    for (int s = 0; s < CH; s++) {
        float dtv = dty[base];
        float xv  = x[base];
        const float4* p4 = (const float4*)(xprow + R_);
        float4 b0 = p4[0], b1 = p4[1], b2 = p4[2], b3 = p4[3];
        float4 c0 = p4[4], c1 = p4[5], c2 = p4[6], c3 = p4[7];
        xprow += E_;
        float bv[16] = {b0.x,b0.y,b0.z,b0.w, b1.x,b1.y,b1.z,b1.w,
                        b2.x,b2.y,b2.z,b2.w, b3.x,b3.y,b3.z,b3.w};
        float cv[16] = {c0.x,c0.y,c0.z,c0.w, c1.x,c1.y,c1.z,c1.w,
                        c2.x,c2.y,c2.z,c2.w, c3.x,c3.y,c3.z,c3.w};
        float u = dtv * xv;
        float y0 = 0.f, y1 = 0.f, y2 = 0.f, y3 = 0.f;
#pragma unroll
        for (int n = 0; n < 16; n += 4) {
            float dA0 = EXP2F(dtv * a2[n + 0]);
            float dA1 = EXP2F(dtv * a2[n + 1]);
            float dA2 = EXP2F(dtv * a2[n + 2]);
            float dA3 = EXP2F(dtv * a2[n + 3]);
            h[n + 0] = fmaf(dA0, h[n + 0], u * bv[n + 0]);
            h[n + 1] = fmaf(dA1, h[n + 1], u * bv[n + 1]);
            h[n + 2] = fmaf(dA2, h[n + 2], u * bv[n + 2]);
            h[n + 3] = fmaf(dA3, h[n + 3], u * bv[n + 3]);
            y0 = fmaf(h[n + 0], cv[n + 0], y0);
            y1 = fmaf(h[n + 1], cv[n + 1], y1);
            y2 = fmaf(h[n + 2], cv[n + 2], y2);
            y3 = fmaf(h[n + 3], cv[n + 3], y3);
        }
        float y = (y0 + y1) + (y2 + y3);
        dty[base] = fmaf(xv, dsk, y);   // overwrite dt with final y
        base += D_;
    }
}

// ---------------------------------------------------------------------------
extern "C" void kernel_launch(void* const* d_in, const int* in_sizes, int n_in,
                              void* d_out, int out_size, void* d_ws, size_t ws_size,
                              hipStream_t stream) {
    const float* x     = (const float*)d_in[0];
    const float* A_log = (const float*)d_in[1];
    const float* Dskip = (const float*)d_in[2];
    const float* Wx    = (const float*)d_in[3];
    const float* Wdt   = (const float*)d_in[4];
    const float* bdt   = (const float*)d_in[5];
    float* out = (float*)d_out;

    float* ws   = (float*)d_ws;
    float* A2   = ws;                       // 32768 floats
    float* xp   = A2 + 32768;               // 16384*96 = 1572864 floats
    float* hend = xp + 1572864;             // 4*32*2048*16 = 4194304 floats
    float* sdtb = hend + 4194304;           // 4*32*2048 = 262144 floats
    ushort* Bh  = (ushort*)(sdtb + 262144); // 196608 ushorts
    ushort* Bl  = Bh + 196608;              // 196608 ushorts
    // total ~24.6 MB of workspace

    hipLaunchKernelGGL(k_prep, dim3(128), dim3(256), 0, stream, A_log, A2);
    hipLaunchKernelGGL(k_packB, dim3(768), dim3(256), 0, stream, Wx, Bh, Bl);
    hipLaunchKernelGGL(k_projm, dim3(512), dim3(256), 0, stream, x, Bh, Bl, xp);
    hipLaunchKernelGGL(k_dt, dim3(512, 16), dim3(256), 0, stream, xp, Wdt, bdt, out);
    hipLaunchKernelGGL(k_scan1, dim3(B_ * NCH * 8), dim3(256), 0, stream,
                       out, x, xp, A2, hend, sdtb);
    hipLaunchKernelGGL(k_comb, dim3((B_ * D_ * N_) / 256), dim3(256), 0, stream,
                       A2, sdtb, hend);
    hipLaunchKernelGGL(k_scan2, dim3(B_ * NCH * 8), dim3(256), 0, stream,
                       out, x, xp, A2, hend, Dskip);
}

// Round 4
// 453.762 us; speedup vs baseline: 1.4200x; 1.0488x over previous
//
#include <hip/hip_runtime.h>
#include <hip/hip_bf16.h>
#include <math.h>

// Problem dims (fixed by the reference)
#define B_   4
#define L_   4096
#define D_   2048
#define N_   16
#define R_   64          // DT_RANK
#define E_   96          // R_ + 2*N_
#define NCH  32          // chunks over L
#define CH   (L_ / NCH)  // 128 steps per chunk

#define LOG2E 1.44269504088896340736f

#if __has_builtin(__builtin_amdgcn_exp2f)
#define EXP2F(x) __builtin_amdgcn_exp2f(x)
#else
#define EXP2F(x) exp2f(x)
#endif

typedef __attribute__((ext_vector_type(8))) short short8v;   // 8 bf16 (4 VGPR)
typedef __attribute__((ext_vector_type(4))) float float4v;   // MFMA C/D

// ---------------------------------------------------------------------------
// K0: A2[d][n] = -exp(A_log[d][n]) * log2(e)   (so dA = exp2(dt * A2))
// ---------------------------------------------------------------------------
__global__ void k_prep(const float* __restrict__ A_log, float* __restrict__ A2) {
    int i = blockIdx.x * 256 + threadIdx.x;
    if (i < D_ * N_) A2[i] = -__expf(A_log[i]) * LOG2E;
}

// ---------------------------------------------------------------------------
// K0b: pack W_x into MFMA B-fragment order, split hi/lo bf16.
// B frag (16x16x32): lane l, elem j -> B[k = s*32 + (l>>4)*8 + j][col = c*16 + (l&15)]
// index: ((c*64 + s)*64 + l)*8 + j   (c=coltile 0..5, s=kstep 0..63)
// ---------------------------------------------------------------------------
__global__ void k_packB(const float* __restrict__ Wx,
                        ushort* __restrict__ Bh, ushort* __restrict__ Bl) {
    int i = blockIdx.x * 256 + threadIdx.x;   // 0 .. 6*64*64*8-1
    int j = i & 7;
    int l = (i >> 3) & 63;
    int s = (i >> 9) & 63;
    int c = i >> 15;                           // 0..5
    int k   = s * 32 + ((l >> 4) << 3) + j;
    int col = c * 16 + (l & 15);
    float v = Wx[(size_t)k * 96 + col];
    unsigned int b  = __float_as_uint(v);
    unsigned int hb = b & 0xFFFF0000u;         // truncated bf16 (exact residual)
    float dl = v - __uint_as_float(hb);
    Bh[i] = (ushort)(hb >> 16);
    Bl[i] = (ushort)(__float_as_uint(dl) >> 16);
}

// ---------------------------------------------------------------------------
// K1: xp = x @ W_x  via split-bf16 MFMA (3 mfma per tile: hh + hl + lh)
// block: 256 thr = 4 waves = 2 row-groups x 2 K-halves; tile M=32, all 96 cols
// ---------------------------------------------------------------------------
__global__ __launch_bounds__(256) void k_projm(const float* __restrict__ x,
                                               const ushort* __restrict__ Bh,
                                               const ushort* __restrict__ Bl,
                                               float* __restrict__ xp) {
    __shared__ float red[2][64][24];   // K-half-1 partials: [rowgrp][lane][6*4]
    const int t    = threadIdx.x;
    const int lane = t & 63;
    const int w    = t >> 6;     // 0..3
    const int rg   = w & 1;      // row group
    const int kh   = w >> 1;     // K half
    const int row0 = blockIdx.x * 32 + rg * 16;
    const int r    = lane & 15;
    const int ko   = (lane >> 4) << 3;   // 0,8,16,24 within the 32-K step

    float4v acc[6];
#pragma unroll
    for (int c = 0; c < 6; c++) acc[c] = (float4v)(0.f);

    const float* xrow = x + (size_t)(row0 + r) * 2048 + kh * 1024 + ko;

#pragma unroll 2
    for (int sl = 0; sl < 32; ++sl) {
        float4 xa = *(const float4*)(xrow);
        float4 xb = *(const float4*)(xrow + 4);
        xrow += 32;
        short8v ah, al;
        {
            float xs8[8] = {xa.x, xa.y, xa.z, xa.w, xb.x, xb.y, xb.z, xb.w};
#pragma unroll
            for (int j = 0; j < 8; j++) {
                unsigned int b  = __float_as_uint(xs8[j]);
                unsigned int hb = b & 0xFFFF0000u;
                ah[j] = (short)(hb >> 16);
                float dl = xs8[j] - __uint_as_float(hb);
                al[j] = (short)(__float_as_uint(dl) >> 16);
            }
        }
        const int s = kh * 32 + sl;
        const ushort* bhp = Bh + ((size_t)s * 64 + lane) * 8;
        const ushort* blp = Bl + ((size_t)s * 64 + lane) * 8;
#pragma unroll
        for (int c = 0; c < 6; c++) {
            short8v bh = *(const short8v*)(bhp + (size_t)c * 32768);
            short8v bl = *(const short8v*)(blp + (size_t)c * 32768);
            acc[c] = __builtin_amdgcn_mfma_f32_16x16x32_bf16(ah, bh, acc[c], 0, 0, 0);
            acc[c] = __builtin_amdgcn_mfma_f32_16x16x32_bf16(ah, bl, acc[c], 0, 0, 0);
            acc[c] = __builtin_amdgcn_mfma_f32_16x16x32_bf16(al, bh, acc[c], 0, 0, 0);
        }
    }

    // combine K halves: kh==1 waves dump partials to LDS, kh==0 waves add+store
    if (kh == 1) {
#pragma unroll
        for (int c = 0; c < 6; c++)
            *(float4*)&red[rg][lane][c * 4] = make_float4(acc[c][0], acc[c][1],
                                                          acc[c][2], acc[c][3]);
    }
    __syncthreads();
    if (kh == 0) {
#pragma unroll
        for (int c = 0; c < 6; c++) {
            float4 o = *(const float4*)&red[rg][lane][c * 4];
            float v0 = acc[c][0] + o.x;
            float v1 = acc[c][1] + o.y;
            float v2 = acc[c][2] + o.z;
            float v3 = acc[c][3] + o.w;
            // D layout: col = lane&15, row = (lane>>4)*4 + j
            int col = c * 16 + (lane & 15);
            size_t rowb = (size_t)(row0 + ((lane >> 4) << 2));
            xp[(rowb + 0) * 96 + col] = v0;
            xp[(rowb + 1) * 96 + col] = v1;
            xp[(rowb + 2) * 96 + col] = v2;
            xp[(rowb + 3) * 96 + col] = v3;
        }
    }
}

// ---------------------------------------------------------------------------
// K2: dt = softplus(xp[:, :64] @ W_dt + b_dt) -> written into d_out (staging)
// Restructured: 64x128 tile, thread = 4x8, b128 LDS reads, 3 reads / 32 FMA.
// ---------------------------------------------------------------------------
__global__ __launch_bounds__(256) void k_dt(const float* __restrict__ xp,
                                            const float* __restrict__ Wdt,
                                            const float* __restrict__ bdt,
                                            float* __restrict__ dt) {
    __shared__ float as[64][72];    // [k][row], stride 72 floats (16B-aligned rows)
    __shared__ float ws2[64][128];  // [k][col]
    const int t  = threadIdx.x;
    const int tx = t & 15;          // col group 0..15 -> cols tx*8..tx*8+7
    const int ty = t >> 4;          // row group 0..15 -> rows ty*4..ty*4+3
    const int m0 = blockIdx.x * 64;
    const int n0 = blockIdx.y * 128;

    {   // A tile: 64 rows x 64 k (dt_low part of xp), transposed into LDS
        int row = t & 63;
        int kq  = (t >> 6) * 16;    // 0,16,32,48
        const float4* p = (const float4*)(xp + (size_t)(m0 + row) * 96 + kq);
#pragma unroll
        for (int q4 = 0; q4 < 4; q4++) {
            float4 v = p[q4];
            as[kq + q4 * 4 + 0][row] = v.x;
            as[kq + q4 * 4 + 1][row] = v.y;
            as[kq + q4 * 4 + 2][row] = v.z;
            as[kq + q4 * 4 + 3][row] = v.w;
        }
    }
    {   // W tile 64x128, coalesced
#pragma unroll
        for (int j = 0; j < 8; j++) {
            int ci = t + j * 256;        // 0..2047 float4-chunks
            int kk = ci >> 5;            // 0..63
            int cc = (ci & 31) * 4;      // 0..124
            float4 v = *(const float4*)(Wdt + (size_t)kk * 2048 + n0 + cc);
            *(float4*)&ws2[kk][cc] = v;
        }
    }
    __syncthreads();

    float acc[4][8];
#pragma unroll
    for (int i = 0; i < 4; i++)
#pragma unroll
        for (int j = 0; j < 8; j++) acc[i][j] = 0.f;

#pragma unroll 4
    for (int k = 0; k < 64; k++) {
        float4 a4 = *(const float4*)&as[k][ty * 4];
        float4 w0 = *(const float4*)&ws2[k][tx * 8];
        float4 w1 = *(const float4*)&ws2[k][tx * 8 + 4];
        float a[4] = {a4.x, a4.y, a4.z, a4.w};
        float wv[8] = {w0.x, w0.y, w0.z, w0.w, w1.x, w1.y, w1.z, w1.w};
#pragma unroll
        for (int i = 0; i < 4; i++)
#pragma unroll
            for (int j = 0; j < 8; j++)
                acc[i][j] = fmaf(a[i], wv[j], acc[i][j]);
    }

    // epilogue: + b_dt, softplus, coalesced stores
    float bv[8];
    {
        float4 b0 = *(const float4*)(bdt + n0 + tx * 8);
        float4 b1 = *(const float4*)(bdt + n0 + tx * 8 + 4);
        bv[0]=b0.x; bv[1]=b0.y; bv[2]=b0.z; bv[3]=b0.w;
        bv[4]=b1.x; bv[5]=b1.y; bv[6]=b1.z; bv[7]=b1.w;
    }
#pragma unroll
    for (int i = 0; i < 4; i++) {
        float o[8];
#pragma unroll
        for (int j = 0; j < 8; j++) {
            float z = acc[i][j] + bv[j];
            o[j] = (z > 20.f) ? z : log1pf(__expf(z));
        }
        size_t rowb = (size_t)(m0 + ty * 4 + i) * 2048 + n0 + tx * 8;
        *(float4*)(dt + rowb)     = make_float4(o[0], o[1], o[2], o[3]);
        *(float4*)(dt + rowb + 4) = make_float4(o[4], o[5], o[6], o[7]);
    }
}

// ---------------------------------------------------------------------------
// K3: scan pass 1 — per chunk: local h (h0=0) and sum(dt) over the chunk
// ---------------------------------------------------------------------------
__global__ __launch_bounds__(256) void k_scan1(const float* __restrict__ dt,
                                               const float* __restrict__ x,
                                               const float* __restrict__ xp,
                                               const float* __restrict__ A2,
                                               float* __restrict__ hend,
                                               float* __restrict__ sdtb) {
    const int t = threadIdx.x;
    int bb = blockIdx.x;
    const int dtile = bb & 7;  bb >>= 3;
    const int c     = bb & 31; bb >>= 5;
    const int b     = bb;
    const int d = dtile * 256 + t;

    float a2[16];
    {
        const float4* p = (const float4*)(A2 + (size_t)d * 16);
        float4 v0 = p[0], v1 = p[1], v2 = p[2], v3 = p[3];
        a2[0]=v0.x; a2[1]=v0.y; a2[2]=v0.z; a2[3]=v0.w;
        a2[4]=v1.x; a2[5]=v1.y; a2[6]=v1.z; a2[7]=v1.w;
        a2[8]=v2.x; a2[9]=v2.y; a2[10]=v2.z; a2[11]=v2.w;
        a2[12]=v3.x; a2[13]=v3.y; a2[14]=v3.z; a2[15]=v3.w;
    }
    float h[16];
#pragma unroll
    for (int n = 0; n < 16; n++) h[n] = 0.f;
    float sdt = 0.f;

    const int tstart = c * CH;
    size_t base = ((size_t)b * L_ + tstart) * D_ + d;
    const float* xprow = xp + ((size_t)b * L_ + tstart) * E_;

    for (int s = 0; s < CH; s++) {
        float dtv = dt[base];
        float xv  = x[base];
        base += D_;
        const float4* p4 = (const float4*)(xprow + R_);
        float4 b0 = p4[0], b1 = p4[1], b2 = p4[2], b3 = p4[3];
        xprow += E_;
        float bv[16] = {b0.x,b0.y,b0.z,b0.w, b1.x,b1.y,b1.z,b1.w,
                        b2.x,b2.y,b2.z,b2.w, b3.x,b3.y,b3.z,b3.w};
        float u = dtv * xv;
        sdt += dtv;
#pragma unroll
        for (int n = 0; n < 16; n++) {
            float dA = EXP2F(dtv * a2[n]);
            h[n] = fmaf(dA, h[n], u * bv[n]);
        }
    }

    size_t hb = ((((size_t)b * NCH + c) * D_) + d) * N_;
#pragma unroll
    for (int q = 0; q < 4; q++) {
        float4 v = make_float4(h[q*4+0], h[q*4+1], h[q*4+2], h[q*4+3]);
        *(float4*)(hend + hb + q * 4) = v;
    }
    sdtb[((size_t)b * NCH + c) * D_ + d] = sdt;
}

// ---------------------------------------------------------------------------
// K4: chain chunk states: hinit[c] = P[c-1]*hinit[c-1] + hend[c-1]
// ---------------------------------------------------------------------------
__global__ void k_comb(const float* __restrict__ A2,
                       const float* __restrict__ sdtb,
                       float* __restrict__ hend) {
    int g = blockIdx.x * 256 + threadIdx.x;   // 0 .. B*D*N-1
    int n = g & 15;
    int d = (g >> 4) & (D_ - 1);
    int b = g >> 15;
    float a2 = A2[(size_t)d * 16 + n];
    float carry = 0.f;
    for (int c = 0; c < NCH; c++) {
        size_t hi = ((((size_t)b * NCH + c) * D_) + d) * N_ + n;
        float e = hend[hi];
        float p = EXP2F(sdtb[((size_t)b * NCH + c) * D_ + d] * a2);
        hend[hi] = carry;                 // now holds hinit for chunk c
        carry = fmaf(p, carry, e);
    }
}

// ---------------------------------------------------------------------------
// K5: scan pass 2 — h starts at hinit, emit y = scan + x*D_skip
// ---------------------------------------------------------------------------
__global__ __launch_bounds__(256) void k_scan2(float* __restrict__ dty,
                                               const float* __restrict__ x,
                                               const float* __restrict__ xp,
                                               const float* __restrict__ A2,
                                               const float* __restrict__ hinit,
                                               const float* __restrict__ Dskip) {
    const int t = threadIdx.x;
    int bb = blockIdx.x;
    const int dtile = bb & 7;  bb >>= 3;
    const int c     = bb & 31; bb >>= 5;
    const int b     = bb;
    const int d = dtile * 256 + t;

    float a2[16];
    {
        const float4* p = (const float4*)(A2 + (size_t)d * 16);
        float4 v0 = p[0], v1 = p[1], v2 = p[2], v3 = p[3];
        a2[0]=v0.x; a2[1]=v0.y; a2[2]=v0.z; a2[3]=v0.w;
        a2[4]=v1.x; a2[5]=v1.y; a2[6]=v1.z; a2[7]=v1.w;
        a2[8]=v2.x; a2[9]=v2.y; a2[10]=v2.z; a2[11]=v2.w;
        a2[12]=v3.x; a2[13]=v3.y; a2[14]=v3.z; a2[15]=v3.w;
    }
    float h[16];
    {
        size_t hb = ((((size_t)b * NCH + c) * D_) + d) * N_;
        const float4* p = (const float4*)(hinit + hb);
        float4 v0 = p[0], v1 = p[1], v2 = p[2], v3 = p[3];
        h[0]=v0.x; h[1]=v0.y; h[2]=v0.z; h[3]=v0.w;
        h[4]=v1.x; h[5]=v1.y; h[6]=v1.z; h[7]=v1.w;
        h[8]=v2.x; h[9]=v2.y; h[10]=v2.z; h[11]=v2.w;
        h[12]=v3.x; h[13]=v3.y; h[14]=v3.z; h[15]=v3.w;
    }
    const float dsk = Dskip[d];

    const int tstart = c * CH;
    size_t base = ((size_t)b * L_ + tstart) * D_ + d;
    const float* xprow = xp + ((size_t)b * L_ + tstart) * E_;

    for (int s = 0; s < CH; s++) {
        float dtv = dty[base];
        float xv  = x[base];
        const float4* p4 = (const float4*)(xprow + R_);
        float4 b0 = p4[0], b1 = p4[1], b2 = p4[2], b3 = p4[3];
        float4 c0 = p4[4], c1 = p4[5], c2 = p4[6], c3 = p4[7];
        xprow += E_;
        float bv[16] = {b0.x,b0.y,b0.z,b0.w, b1.x,b1.y,b1.z,b1.w,
                        b2.x,b2.y,b2.z,b2.w, b3.x,b3.y,b3.z,b3.w};
        float cv[16] = {c0.x,c0.y,c0.z,c0.w, c1.x,c1.y,c1.z,c1.w,
                        c2.x,c2.y,c2.z,c2.w, c3.x,c3.y,c3.z,c3.w};
        float u = dtv * xv;
        float y0 = 0.f, y1 = 0.f, y2 = 0.f, y3 = 0.f;
#pragma unroll
        for (int n = 0; n < 16; n += 4) {
            float dA0 = EXP2F(dtv * a2[n + 0]);
            float dA1 = EXP2F(dtv * a2[n + 1]);
            float dA2 = EXP2F(dtv * a2[n + 2]);
            float dA3 = EXP2F(dtv * a2[n + 3]);
            h[n + 0] = fmaf(dA0, h[n + 0], u * bv[n + 0]);
            h[n + 1] = fmaf(dA1, h[n + 1], u * bv[n + 1]);
            h[n + 2] = fmaf(dA2, h[n + 2], u * bv[n + 2]);
            h[n + 3] = fmaf(dA3, h[n + 3], u * bv[n + 3]);
            y0 = fmaf(h[n + 0], cv[n + 0], y0);
            y1 = fmaf(h[n + 1], cv[n + 1], y1);
            y2 = fmaf(h[n + 2], cv[n + 2], y2);
            y3 = fmaf(h[n + 3], cv[n + 3], y3);
        }
        float y = (y0 + y1) + (y2 + y3);
        dty[base] = fmaf(xv, dsk, y);   // overwrite dt with final y
        base += D_;
    }
}

// ---------------------------------------------------------------------------
extern "C" void kernel_launch(void* const* d_in, const int* in_sizes, int n_in,
                              void* d_out, int out_size, void* d_ws, size_t ws_size,
                              hipStream_t stream) {
    const float* x     = (const float*)d_in[0];
    const float* A_log = (const float*)d_in[1];
    const float* Dskip = (const float*)d_in[2];
    const float* Wx    = (const float*)d_in[3];
    const float* Wdt   = (const float*)d_in[4];
    const float* bdt   = (const float*)d_in[5];
    float* out = (float*)d_out;

    float* ws   = (float*)d_ws;
    float* A2   = ws;                       // 32768 floats
    float* xp   = A2 + 32768;               // 16384*96 = 1572864 floats
    float* hend = xp + 1572864;             // 4*32*2048*16 = 4194304 floats
    float* sdtb = hend + 4194304;           // 4*32*2048 = 262144 floats
    ushort* Bh  = (ushort*)(sdtb + 262144); // 196608 ushorts
    ushort* Bl  = Bh + 196608;              // 196608 ushorts
    // total ~24.6 MB of workspace

    hipLaunchKernelGGL(k_prep, dim3(128), dim3(256), 0, stream, A_log, A2);
    hipLaunchKernelGGL(k_packB, dim3(768), dim3(256), 0, stream, Wx, Bh, Bl);
    hipLaunchKernelGGL(k_projm, dim3(512), dim3(256), 0, stream, x, Bh, Bl, xp);
    hipLaunchKernelGGL(k_dt, dim3(256, 16), dim3(256), 0, stream, xp, Wdt, bdt, out);
    hipLaunchKernelGGL(k_scan1, dim3(B_ * NCH * 8), dim3(256), 0, stream,
                       out, x, xp, A2, hend, sdtb);
    hipLaunchKernelGGL(k_comb, dim3((B_ * D_ * N_) / 256), dim3(256), 0, stream,
                       A2, sdtb, hend);
    hipLaunchKernelGGL(k_scan2, dim3(B_ * NCH * 8), dim3(256), 0, stream,
                       out, x, xp, A2, hend, Dskip);
}

// Round 5
// 371.668 us; speedup vs baseline: 1.7336x; 1.2209x over previous
//
#include <hip/hip_runtime.h>
#include <hip/hip_bf16.h>
#include <math.h>

// Problem dims (fixed by the reference)
#define B_   4
#define L_   4096
#define D_   2048
#define N_   16
#define R_   64          // DT_RANK
#define E_   96          // R_ + 2*N_
#define NCH  32          // chunks over L
#define CH   (L_ / NCH)  // 128 steps per chunk

#define LOG2E 1.44269504088896340736f

#if __has_builtin(__builtin_amdgcn_exp2f)
#define EXP2F(x) __builtin_amdgcn_exp2f(x)
#else
#define EXP2F(x) exp2f(x)
#endif

typedef __attribute__((ext_vector_type(8))) short short8v;   // 8 bf16 (4 VGPR)
typedef __attribute__((ext_vector_type(4))) float float4v;   // MFMA C/D

// ---------------------------------------------------------------------------
// K0: A2[d][n] = -exp(A_log[d][n]) * log2(e)   (so dA = exp2(dt * A2))
// ---------------------------------------------------------------------------
__global__ void k_prep(const float* __restrict__ A_log, float* __restrict__ A2) {
    int i = blockIdx.x * 256 + threadIdx.x;
    if (i < D_ * N_) A2[i] = -__expf(A_log[i]) * LOG2E;
}

// ---------------------------------------------------------------------------
// K0b: pack W_x into MFMA B-fragment order, split hi/lo bf16.
// B frag (16x16x32): lane l, elem j -> B[k = s*32 + (l>>4)*8 + j][col = c*16 + (l&15)]
// index: ((c*64 + s)*64 + l)*8 + j   (c=coltile 0..5, s=kstep 0..63)
// ---------------------------------------------------------------------------
__global__ void k_packB(const float* __restrict__ Wx,
                        ushort* __restrict__ Bh, ushort* __restrict__ Bl) {
    int i = blockIdx.x * 256 + threadIdx.x;   // 0 .. 6*64*64*8-1
    int j = i & 7;
    int l = (i >> 3) & 63;
    int s = (i >> 9) & 63;
    int c = i >> 15;                           // 0..5
    int k   = s * 32 + ((l >> 4) << 3) + j;
    int col = c * 16 + (l & 15);
    float v = Wx[(size_t)k * 96 + col];
    unsigned int b  = __float_as_uint(v);
    unsigned int hb = b & 0xFFFF0000u;         // truncated bf16 (exact residual)
    float dl = v - __uint_as_float(hb);
    Bh[i] = (ushort)(hb >> 16);
    Bl[i] = (ushort)(__float_as_uint(dl) >> 16);
}

// ---------------------------------------------------------------------------
// K0c: pack W_dt (64 x 2048) into MFMA B-fragment order, split hi/lo bf16.
// coltile c = 0..127, kstep s = 0..1: index ((c*2 + s)*64 + l)*8 + j
// ---------------------------------------------------------------------------
__global__ void k_packW(const float* __restrict__ Wdt,
                        ushort* __restrict__ Wh, ushort* __restrict__ Wl) {
    int i = blockIdx.x * 256 + threadIdx.x;   // 0 .. 128*2*64*8-1 = 131071
    int j = i & 7;
    int l = (i >> 3) & 63;
    int s = (i >> 9) & 1;
    int c = i >> 10;                           // 0..127
    int k   = s * 32 + ((l >> 4) << 3) + j;
    int col = c * 16 + (l & 15);
    float v = Wdt[(size_t)k * 2048 + col];
    unsigned int b  = __float_as_uint(v);
    unsigned int hb = b & 0xFFFF0000u;
    float dl = v - __uint_as_float(hb);
    Wh[i] = (ushort)(hb >> 16);
    Wl[i] = (ushort)(__float_as_uint(dl) >> 16);
}

// ---------------------------------------------------------------------------
// K1: xp = x @ W_x  via split-bf16 MFMA (3 mfma per tile: hh + hl + lh)
// block: 256 thr = 4 waves = 2 row-groups x 2 K-halves; tile M=32, all 96 cols
// ---------------------------------------------------------------------------
__global__ __launch_bounds__(256) void k_projm(const float* __restrict__ x,
                                               const ushort* __restrict__ Bh,
                                               const ushort* __restrict__ Bl,
                                               float* __restrict__ xp) {
    __shared__ float red[2][64][24];   // K-half-1 partials: [rowgrp][lane][6*4]
    const int t    = threadIdx.x;
    const int lane = t & 63;
    const int w    = t >> 6;     // 0..3
    const int rg   = w & 1;      // row group
    const int kh   = w >> 1;     // K half
    const int row0 = blockIdx.x * 32 + rg * 16;
    const int r    = lane & 15;
    const int ko   = (lane >> 4) << 3;   // 0,8,16,24 within the 32-K step

    float4v acc[6];
#pragma unroll
    for (int c = 0; c < 6; c++) acc[c] = (float4v)(0.f);

    const float* xrow = x + (size_t)(row0 + r) * 2048 + kh * 1024 + ko;

#pragma unroll 2
    for (int sl = 0; sl < 32; ++sl) {
        float4 xa = *(const float4*)(xrow);
        float4 xb = *(const float4*)(xrow + 4);
        xrow += 32;
        short8v ah, al;
        {
            float xs8[8] = {xa.x, xa.y, xa.z, xa.w, xb.x, xb.y, xb.z, xb.w};
#pragma unroll
            for (int j = 0; j < 8; j++) {
                unsigned int b  = __float_as_uint(xs8[j]);
                unsigned int hb = b & 0xFFFF0000u;
                ah[j] = (short)(hb >> 16);
                float dl = xs8[j] - __uint_as_float(hb);
                al[j] = (short)(__float_as_uint(dl) >> 16);
            }
        }
        const int s = kh * 32 + sl;
        const ushort* bhp = Bh + ((size_t)s * 64 + lane) * 8;
        const ushort* blp = Bl + ((size_t)s * 64 + lane) * 8;
#pragma unroll
        for (int c = 0; c < 6; c++) {
            short8v bh = *(const short8v*)(bhp + (size_t)c * 32768);
            short8v bl = *(const short8v*)(blp + (size_t)c * 32768);
            acc[c] = __builtin_amdgcn_mfma_f32_16x16x32_bf16(ah, bh, acc[c], 0, 0, 0);
            acc[c] = __builtin_amdgcn_mfma_f32_16x16x32_bf16(ah, bl, acc[c], 0, 0, 0);
            acc[c] = __builtin_amdgcn_mfma_f32_16x16x32_bf16(al, bh, acc[c], 0, 0, 0);
        }
    }

    // combine K halves: kh==1 waves dump partials to LDS, kh==0 waves add+store
    if (kh == 1) {
#pragma unroll
        for (int c = 0; c < 6; c++)
            *(float4*)&red[rg][lane][c * 4] = make_float4(acc[c][0], acc[c][1],
                                                          acc[c][2], acc[c][3]);
    }
    __syncthreads();
    if (kh == 0) {
#pragma unroll
        for (int c = 0; c < 6; c++) {
            float4 o = *(const float4*)&red[rg][lane][c * 4];
            float v0 = acc[c][0] + o.x;
            float v1 = acc[c][1] + o.y;
            float v2 = acc[c][2] + o.z;
            float v3 = acc[c][3] + o.w;
            // D layout: col = lane&15, row = (lane>>4)*4 + j
            int col = c * 16 + (lane & 15);
            size_t rowb = (size_t)(row0 + ((lane >> 4) << 2));
            xp[(rowb + 0) * 96 + col] = v0;
            xp[(rowb + 1) * 96 + col] = v1;
            xp[(rowb + 2) * 96 + col] = v2;
            xp[(rowb + 3) * 96 + col] = v3;
        }
    }
}

// ---------------------------------------------------------------------------
// K2: dt = softplus(xp[:, :64] @ W_dt + b_dt) via split-bf16 MFMA.
// block: 256 thr = 4 waves stacked in M; wave tile = 16 rows x 128 cols.
// grid (256, 16): M = 16384, N = 2048. No LDS. W_dt pre-packed (L2-resident).
// ---------------------------------------------------------------------------
__global__ __launch_bounds__(256) void k_dtm(const float* __restrict__ xp,
                                             const ushort* __restrict__ Wh,
                                             const ushort* __restrict__ Wl,
                                             const float* __restrict__ bdt,
                                             float* __restrict__ dt) {
    const int t    = threadIdx.x;
    const int lane = t & 63;
    const int w    = t >> 6;                 // 0..3
    const int row0 = blockIdx.x * 64 + w * 16;
    const int n0   = blockIdx.y * 128;
    const int ct0  = blockIdx.y * 8;         // first col tile
    const int r    = lane & 15;
    const int ko   = (lane >> 4) << 3;       // 0,8,16,24

    // A fragments for both K-steps (K=64 -> s=0,1), split hi/lo
    short8v ah[2], al[2];
#pragma unroll
    for (int s = 0; s < 2; s++) {
        const float* ap = xp + (size_t)(row0 + r) * 96 + s * 32 + ko;
        float4 xa = *(const float4*)(ap);
        float4 xb = *(const float4*)(ap + 4);
        float xs8[8] = {xa.x, xa.y, xa.z, xa.w, xb.x, xb.y, xb.z, xb.w};
#pragma unroll
        for (int j = 0; j < 8; j++) {
            unsigned int b  = __float_as_uint(xs8[j]);
            unsigned int hb = b & 0xFFFF0000u;
            ah[s][j] = (short)(hb >> 16);
            float dl = xs8[j] - __uint_as_float(hb);
            al[s][j] = (short)(__float_as_uint(dl) >> 16);
        }
    }

    float4v acc[8];
#pragma unroll
    for (int c = 0; c < 8; c++) acc[c] = (float4v)(0.f);

#pragma unroll
    for (int s = 0; s < 2; s++) {
#pragma unroll
        for (int c = 0; c < 8; c++) {
            size_t fi = (((size_t)(ct0 + c) * 2 + s) * 64 + lane) * 8;
            short8v bh = *(const short8v*)(Wh + fi);
            short8v bl = *(const short8v*)(Wl + fi);
            acc[c] = __builtin_amdgcn_mfma_f32_16x16x32_bf16(ah[s], bh, acc[c], 0, 0, 0);
            acc[c] = __builtin_amdgcn_mfma_f32_16x16x32_bf16(ah[s], bl, acc[c], 0, 0, 0);
            acc[c] = __builtin_amdgcn_mfma_f32_16x16x32_bf16(al[s], bh, acc[c], 0, 0, 0);
        }
    }

    // epilogue: +b_dt, softplus, store. D layout: col=lane&15, row=(lane>>4)*4+j
    const int colb = n0 + (lane & 15);
    const int rowg = row0 + ((lane >> 4) << 2);
#pragma unroll
    for (int c = 0; c < 8; c++) {
        int col = colb + c * 16;
        float bb = bdt[col];
#pragma unroll
        for (int j = 0; j < 4; j++) {
            float z = acc[c][j] + bb;
            float v = (z > 20.f) ? z : __logf(1.f + __expf(z));
            dt[(size_t)(rowg + j) * 2048 + col] = v;
        }
    }
}

// ---------------------------------------------------------------------------
// K3: scan pass 1 — per chunk: local h (h0=0) and sum(dt) over the chunk
// ---------------------------------------------------------------------------
__global__ __launch_bounds__(256) void k_scan1(const float* __restrict__ dt,
                                               const float* __restrict__ x,
                                               const float* __restrict__ xp,
                                               const float* __restrict__ A2,
                                               float* __restrict__ hend,
                                               float* __restrict__ sdtb) {
    const int t = threadIdx.x;
    int bb = blockIdx.x;
    const int dtile = bb & 7;  bb >>= 3;
    const int c     = bb & 31; bb >>= 5;
    const int b     = bb;
    const int d = dtile * 256 + t;

    float a2[16];
    {
        const float4* p = (const float4*)(A2 + (size_t)d * 16);
        float4 v0 = p[0], v1 = p[1], v2 = p[2], v3 = p[3];
        a2[0]=v0.x; a2[1]=v0.y; a2[2]=v0.z; a2[3]=v0.w;
        a2[4]=v1.x; a2[5]=v1.y; a2[6]=v1.z; a2[7]=v1.w;
        a2[8]=v2.x; a2[9]=v2.y; a2[10]=v2.z; a2[11]=v2.w;
        a2[12]=v3.x; a2[13]=v3.y; a2[14]=v3.z; a2[15]=v3.w;
    }
    float h[16];
#pragma unroll
    for (int n = 0; n < 16; n++) h[n] = 0.f;
    float sdt = 0.f;

    const int tstart = c * CH;
    size_t base = ((size_t)b * L_ + tstart) * D_ + d;
    const float* xprow = xp + ((size_t)b * L_ + tstart) * E_;

    for (int s = 0; s < CH; s++) {
        float dtv = dt[base];
        float xv  = x[base];
        base += D_;
        const float4* p4 = (const float4*)(xprow + R_);
        float4 b0 = p4[0], b1 = p4[1], b2 = p4[2], b3 = p4[3];
        xprow += E_;
        float bv[16] = {b0.x,b0.y,b0.z,b0.w, b1.x,b1.y,b1.z,b1.w,
                        b2.x,b2.y,b2.z,b2.w, b3.x,b3.y,b3.z,b3.w};
        float u = dtv * xv;
        sdt += dtv;
#pragma unroll
        for (int n = 0; n < 16; n++) {
            float dA = EXP2F(dtv * a2[n]);
            h[n] = fmaf(dA, h[n], u * bv[n]);
        }
    }

    size_t hb = ((((size_t)b * NCH + c) * D_) + d) * N_;
#pragma unroll
    for (int q = 0; q < 4; q++) {
        float4 v = make_float4(h[q*4+0], h[q*4+1], h[q*4+2], h[q*4+3]);
        *(float4*)(hend + hb + q * 4) = v;
    }
    sdtb[((size_t)b * NCH + c) * D_ + d] = sdt;
}

// ---------------------------------------------------------------------------
// K4: chain chunk states: hinit[c] = P[c-1]*hinit[c-1] + hend[c-1]
// ---------------------------------------------------------------------------
__global__ void k_comb(const float* __restrict__ A2,
                       const float* __restrict__ sdtb,
                       float* __restrict__ hend) {
    int g = blockIdx.x * 256 + threadIdx.x;   // 0 .. B*D*N-1
    int n = g & 15;
    int d = (g >> 4) & (D_ - 1);
    int b = g >> 15;
    float a2 = A2[(size_t)d * 16 + n];
    float carry = 0.f;
    for (int c = 0; c < NCH; c++) {
        size_t hi = ((((size_t)b * NCH + c) * D_) + d) * N_ + n;
        float e = hend[hi];
        float p = EXP2F(sdtb[((size_t)b * NCH + c) * D_ + d] * a2);
        hend[hi] = carry;                 // now holds hinit for chunk c
        carry = fmaf(p, carry, e);
    }
}

// ---------------------------------------------------------------------------
// K5: scan pass 2 — h starts at hinit, emit y = scan + x*D_skip
// ---------------------------------------------------------------------------
__global__ __launch_bounds__(256) void k_scan2(float* __restrict__ dty,
                                               const float* __restrict__ x,
                                               const float* __restrict__ xp,
                                               const float* __restrict__ A2,
                                               const float* __restrict__ hinit,
                                               const float* __restrict__ Dskip) {
    const int t = threadIdx.x;
    int bb = blockIdx.x;
    const int dtile = bb & 7;  bb >>= 3;
    const int c     = bb & 31; bb >>= 5;
    const int b     = bb;
    const int d = dtile * 256 + t;

    float a2[16];
    {
        const float4* p = (const float4*)(A2 + (size_t)d * 16);
        float4 v0 = p[0], v1 = p[1], v2 = p[2], v3 = p[3];
        a2[0]=v0.x; a2[1]=v0.y; a2[2]=v0.z; a2[3]=v0.w;
        a2[4]=v1.x; a2[5]=v1.y; a2[6]=v1.z; a2[7]=v1.w;
        a2[8]=v2.x; a2[9]=v2.y; a2[10]=v2.z; a2[11]=v2.w;
        a2[12]=v3.x; a2[13]=v3.y; a2[14]=v3.z; a2[15]=v3.w;
    }
    float h[16];
    {
        size_t hb = ((((size_t)b * NCH + c) * D_) + d) * N_;
        const float4* p = (const float4*)(hinit + hb);
        float4 v0 = p[0], v1 = p[1], v2 = p[2], v3 = p[3];
        h[0]=v0.x; h[1]=v0.y; h[2]=v0.z; h[3]=v0.w;
        h[4]=v1.x; h[5]=v1.y; h[6]=v1.z; h[7]=v1.w;
        h[8]=v2.x; h[9]=v2.y; h[10]=v2.z; h[11]=v2.w;
        h[12]=v3.x; h[13]=v3.y; h[14]=v3.z; h[15]=v3.w;
    }
    const float dsk = Dskip[d];

    const int tstart = c * CH;
    size_t base = ((size_t)b * L_ + tstart) * D_ + d;
    const float* xprow = xp + ((size_t)b * L_ + tstart) * E_;

    for (int s = 0; s < CH; s++) {
        float dtv = dty[base];
        float xv  = x[base];
        const float4* p4 = (const float4*)(xprow + R_);
        float4 b0 = p4[0], b1 = p4[1], b2 = p4[2], b3 = p4[3];
        float4 c0 = p4[4], c1 = p4[5], c2 = p4[6], c3 = p4[7];
        xprow += E_;
        float bv[16] = {b0.x,b0.y,b0.z,b0.w, b1.x,b1.y,b1.z,b1.w,
                        b2.x,b2.y,b2.z,b2.w, b3.x,b3.y,b3.z,b3.w};
        float cv[16] = {c0.x,c0.y,c0.z,c0.w, c1.x,c1.y,c1.z,c1.w,
                        c2.x,c2.y,c2.z,c2.w, c3.x,c3.y,c3.z,c3.w};
        float u = dtv * xv;
        float y0 = 0.f, y1 = 0.f, y2 = 0.f, y3 = 0.f;
#pragma unroll
        for (int n = 0; n < 16; n += 4) {
            float dA0 = EXP2F(dtv * a2[n + 0]);
            float dA1 = EXP2F(dtv * a2[n + 1]);
            float dA2 = EXP2F(dtv * a2[n + 2]);
            float dA3 = EXP2F(dtv * a2[n + 3]);
            h[n + 0] = fmaf(dA0, h[n + 0], u * bv[n + 0]);
            h[n + 1] = fmaf(dA1, h[n + 1], u * bv[n + 1]);
            h[n + 2] = fmaf(dA2, h[n + 2], u * bv[n + 2]);
            h[n + 3] = fmaf(dA3, h[n + 3], u * bv[n + 3]);
            y0 = fmaf(h[n + 0], cv[n + 0], y0);
            y1 = fmaf(h[n + 1], cv[n + 1], y1);
            y2 = fmaf(h[n + 2], cv[n + 2], y2);
            y3 = fmaf(h[n + 3], cv[n + 3], y3);
        }
        float y = (y0 + y1) + (y2 + y3);
        dty[base] = fmaf(xv, dsk, y);   // overwrite dt with final y
        base += D_;
    }
}

// ---------------------------------------------------------------------------
extern "C" void kernel_launch(void* const* d_in, const int* in_sizes, int n_in,
                              void* d_out, int out_size, void* d_ws, size_t ws_size,
                              hipStream_t stream) {
    const float* x     = (const float*)d_in[0];
    const float* A_log = (const float*)d_in[1];
    const float* Dskip = (const float*)d_in[2];
    const float* Wx    = (const float*)d_in[3];
    const float* Wdt   = (const float*)d_in[4];
    const float* bdt   = (const float*)d_in[5];
    float* out = (float*)d_out;

    float* ws   = (float*)d_ws;
    float* A2   = ws;                       // 32768 floats
    float* xp   = A2 + 32768;               // 16384*96 = 1572864 floats
    float* hend = xp + 1572864;             // 4*32*2048*16 = 4194304 floats
    float* sdtb = hend + 4194304;           // 4*32*2048 = 262144 floats
    ushort* Bh  = (ushort*)(sdtb + 262144); // 196608 ushorts (W_x hi frags)
    ushort* Bl  = Bh + 196608;              // 196608 ushorts
    ushort* Wh  = Bl + 196608;              // 131072 ushorts (W_dt hi frags)
    ushort* Wl  = Wh + 131072;              // 131072 ushorts
    // total ~25.1 MB of workspace

    hipLaunchKernelGGL(k_prep, dim3(128), dim3(256), 0, stream, A_log, A2);
    hipLaunchKernelGGL(k_packB, dim3(768), dim3(256), 0, stream, Wx, Bh, Bl);
    hipLaunchKernelGGL(k_packW, dim3(512), dim3(256), 0, stream, Wdt, Wh, Wl);
    hipLaunchKernelGGL(k_projm, dim3(512), dim3(256), 0, stream, x, Bh, Bl, xp);
    hipLaunchKernelGGL(k_dtm, dim3(256, 16), dim3(256), 0, stream, xp, Wh, Wl, bdt, out);
    hipLaunchKernelGGL(k_scan1, dim3(B_ * NCH * 8), dim3(256), 0, stream,
                       out, x, xp, A2, hend, sdtb);
    hipLaunchKernelGGL(k_comb, dim3((B_ * D_ * N_) / 256), dim3(256), 0, stream,
                       A2, sdtb, hend);
    hipLaunchKernelGGL(k_scan2, dim3(B_ * NCH * 8), dim3(256), 0, stream,
                       out, x, xp, A2, hend, Dskip);
}